// Round 6
// baseline (658.989 us; speedup 1.0000x reference)
//
#include <hip/hip_runtime.h>
#include <hip/hip_fp16.h>

// B=32768, D_IN=256, H1=256, D_OUT=64, E=32, T=16
#define NTHR 512
#define BM   128
#define NBLK 256
#define NEXP 32

using f16x8 = __attribute__((ext_vector_type(8))) _Float16;
using f16x4 = __attribute__((ext_vector_type(4))) _Float16;
using f32x4 = __attribute__((ext_vector_type(4))) float;
using u32x4 = __attribute__((ext_vector_type(4))) unsigned int;
using u32x2 = __attribute__((ext_vector_type(2))) unsigned int;

// ---- per-expert stream (bytes): stride 182272 ----
//   [0)      8 x 16KB W1 fragment tiles (kc 0..7)
//   [131072) 24KB WVplus wn0 frags
//   [155648) 24KB WVplus wn1 frags
//   [180224) 1KB b1 (256 f32)
//   [181248) 1KB b2v (80 f32 used)
static constexpr size_t ESTRIDE_B = 182272;   // = 91136 halves

__device__ __forceinline__ unsigned short f2h(float x){
  _Float16 h = (_Float16)x; return __builtin_bit_cast(unsigned short, h);
}

typedef __attribute__((address_space(3))) void lds_void;
typedef const __attribute__((address_space(1))) void glb_void;
__device__ __forceinline__ void gll16(const void* g, void* l){
  __builtin_amdgcn_global_load_lds((glb_void*)g, (lds_void*)l, 16, 0, 0);
}

#define VMW(N)  asm volatile("s_waitcnt vmcnt(" #N ")" ::: "memory")
#define LGKM0   asm volatile("s_waitcnt lgkmcnt(0)" ::: "memory")
#define SB      __builtin_amdgcn_sched_barrier(0)
#define BARRIER do { SB; __builtin_amdgcn_s_barrier(); SB; } while(0)

// ---------------------------------------------------------------------------
// prep 1: W1 [E][256][256] f32 -> per-(e,kc) 16KB fragment tile.
// frag(ct,l,j) = W1[e][kc*32 + (l>>4)*8 + j][ct*16 + (l&15)]
// ---------------------------------------------------------------------------
__global__ __launch_bounds__(256) void prep_w1frag(const float* __restrict__ W1,
                                                   unsigned short* __restrict__ strm){
  const int e = blockIdx.x >> 3, kc = blockIdx.x & 7;
  const float* se = W1 + (size_t)e*65536 + (size_t)kc*32*256;
  unsigned short* de = strm + (size_t)e*91136 + kc*8192;
  for (int fl = threadIdx.x; fl < 1024; fl += 256){
    const int ct = fl >> 6, l = fl & 63;
    const float* s0 = se + (size_t)((l>>4)*8)*256 + ct*16 + (l&15);
    union { unsigned short s[8]; u32x4 v; } h8;
    #pragma unroll
    for (int j = 0; j < 8; j++) h8.s[j] = f2h(s0[(size_t)j*256]);
    *reinterpret_cast<u32x4*>(&de[fl*8]) = h8.v;
  }
}

// ---------------------------------------------------------------------------
// prep 2: WVplus = [ W2@V (64 cols) | fp16-hi of W2@kt (16) | fp16-residual (16) ]
// fragment-pair layout for 16x16x16 B-op. Also b1, b2v into stream.
// grid: 256 blocks = (e, oct of 32 k2-rows)
// ---------------------------------------------------------------------------
__global__ __launch_bounds__(256) void prep_wvp(
    const float* __restrict__ W2, const float* __restrict__ V,
    const float* __restrict__ Km, const float* __restrict__ Q,
    const float* __restrict__ b1, const float* __restrict__ b2,
    unsigned short* __restrict__ strm, float* __restrict__ out)
{
  const int e = blockIdx.x >> 3, oct = blockIdx.x & 7;
  const int t = threadIdx.x;
  __shared__ float lv[64*64];     // V[e]
  __shared__ float ktlT[64*16];   // kt transposed: [i][t]
  __shared__ float lw2[32*64];    // W2 rows oct*32..+31

  for (int i = t; i < 1024; i += 256)
    *reinterpret_cast<float4*>(&lv[i*4]) = *reinterpret_cast<const float4*>(V + (size_t)e*4096 + i*4);
  for (int i = t; i < 512; i += 256)
    *reinterpret_cast<float4*>(&lw2[i*4]) = *reinterpret_cast<const float4*>(W2 + (size_t)e*16384 + (size_t)oct*2048 + i*4);
  #pragma unroll
  for (int pass = 0; pass < 4; pass++){
    const int id = t + pass*256;
    const int tt = id >> 6, i = id & 63;
    const float4* Kr = reinterpret_cast<const float4*>(Km + (size_t)(e*64 + i)*64);
    const float4* qr = reinterpret_cast<const float4*>(Q + tt*64);
    float s = 0.f;
    #pragma unroll
    for (int j = 0; j < 16; j++){ float4 a = Kr[j], b = qr[j]; s += a.x*b.x+a.y*b.y+a.z*b.z+a.w*b.w; }
    ktlT[i*16 + tt] = s;
  }
  __syncthreads();

  const int k2 = oct*32 + (t >> 3);
  const int cb = t & 7;
  const int c0 = cb*12;
  const float* w2r = &lw2[(t>>3)*64];
  const float* gp[3]; int gs[3]; bool gv[3];
  #pragma unroll
  for (int q = 0; q < 3; q++){
    const int cg = c0 + q*4;
    gv[q] = (cg < 80);
    if (cg < 64){ gp[q] = &lv[cg];        gs[q] = 64; }
    else        { gp[q] = &ktlT[cg - 64]; gs[q] = 16; }
  }
  float pv[12];
  #pragma unroll
  for (int n = 0; n < 12; n++) pv[n] = 0.f;
  for (int i = 0; i < 64; i++){
    const float w = w2r[i];
    #pragma unroll
    for (int q = 0; q < 3; q++){
      if (gv[q]){
        const float4 vq = *reinterpret_cast<const float4*>(gp[q] + i*gs[q]);
        pv[q*4+0] += w*vq.x; pv[q*4+1] += w*vq.y; pv[q*4+2] += w*vq.z; pv[q*4+3] += w*vq.w;
      }
    }
  }
  const int wn_ = k2 >> 7, fn = (k2 >> 4) & 7, fnp = fn >> 1, half = fn & 1;
  const int g2 = (k2 >> 2) & 3, jj = k2 & 3;
  unsigned short* fb = strm + (size_t)e*91136 + (wn_ ? 77824 : 65536);
  #pragma unroll
  for (int n = 0; n < 12; n++){
    const int cc = c0 + n;
    if (cc < 64){
      const int ct = cc >> 4, lc = cc & 15, l = g2*16 + lc;
      fb[(fnp*6+ct)*512 + l*8 + half*4 + jj] = f2h(pv[n]);
    } else if (cc < 80){
      const int lc = cc - 64, l = g2*16 + lc;
      const float s = pv[n];
      const unsigned short hi = f2h(s);
      const float rem = s - (float)__builtin_bit_cast(_Float16, hi);
      fb[(fnp*6+4)*512 + l*8 + half*4 + jj] = hi;
      fb[(fnp*6+5)*512 + l*8 + half*4 + jj] = f2h(rem);
    }
  }
  if (oct == 0){
    float* b1d = reinterpret_cast<float*>((char*)strm + (size_t)e*ESTRIDE_B + 180224);
    b1d[t] = b1[e*256 + t];
  }
  if (oct == 1 && t < 80){
    float s = 0.f;
    if (t < 64){ for (int i = 0; i < 64; i++) s += b2[e*64+i]*lv[i*64+t]; }
    else       { for (int i = 0; i < 64; i++) s += b2[e*64+i]*ktlT[i*16 + (t-64)]; }
    float* bd = reinterpret_cast<float*>((char*)strm + (size_t)e*ESTRIDE_B + 181248);
    bd[t] = s;
  }
  if (blockIdx.x == 0 && t == 0) out[2097152] = -10.24032768f;
}

// ---------------------------------------------------------------------------
// main kernel: 256 blocks x 512 thr, 1 block/CU (LDS-limited). 5-slot LDS
// ring, counted-vmcnt stream; LDS->reg B-fragments double-buffered one phase
// ahead. NO __launch_bounds__: amdgpu_waves_per_eu(2,2) pins the allocator
// to 2 waves/EU -> 256-VGPR budget (R5 spilled at the implied 128 cap).
// ---------------------------------------------------------------------------
__global__ __attribute__((amdgpu_flat_work_group_size(NTHR, NTHR), amdgpu_waves_per_eu(2, 2)))
void moe_main(const float* __restrict__ X, const int* __restrict__ task,
              const unsigned short* __restrict__ strm, float* __restrict__ out)
{
  __shared__ unsigned short ring[64000];   // 5 x 12800 halves (25.6KB slots)
  __shared__ unsigned char  exch[24576];

  const int tid  = threadIdx.x;
  const int lane = tid & 63;
  const int wid  = tid >> 6;
  const int g    = lane >> 4;
  const int c    = lane & 15;
  const int wm   = wid >> 1, wn = wid & 1;
  const int row0 = blockIdx.x * BM;

  auto issue16 = [&](const unsigned short* src, int slot){
    unsigned short* d = &ring[slot*12800];
    gll16(src + tid*8,        d + tid*8);
    gll16(src + 4096 + tid*8, d + 4096 + tid*8);
  };
  auto issue24 = [&](const unsigned short* src, int slot){
    unsigned short* d = &ring[slot*12800];
    gll16(src + tid*8,        d + tid*8);
    gll16(src + 4096 + tid*8, d + 4096 + tid*8);
    gll16(src + 8192 + tid*8, d + 8192 + tid*8);
  };
  auto issueAux = [&](const unsigned short* es_){   // b1 -> slot3x, b2v -> slot4x
    gll16(es_ + 90112 + lane*8, &ring[3*12800 + 12288 + lane*8]);
    gll16(es_ + 90624 + lane*8, &ring[4*12800 + 12288 + lane*8]);
  };

  // ---- persistent X A-frags (16 global loads; drained by prologue VMW(6)) ----
  f16x8 af[2][8];
  #pragma unroll
  for (int fm = 0; fm < 2; fm++){
    const float* xr = X + (size_t)(row0 + wm*32 + fm*16 + c)*256;
    #pragma unroll
    for (int kc = 0; kc < 8; kc++){
      const f32x4 v0 = *reinterpret_cast<const f32x4*>(xr + kc*32 + g*8);
      const f32x4 v1 = *reinterpret_cast<const f32x4*>(xr + kc*32 + g*8 + 4);
      union { unsigned short s[8]; f16x8 h; } h8;
      #pragma unroll
      for (int j = 0; j < 4; j++){ h8.s[j] = f2h(v0[j]); h8.s[4+j] = f2h(v1[j]); }
      af[fm][kc] = h8.h;
    }
  }
  const int4 tq = *reinterpret_cast<const int4*>(&task[row0 + wm*32 + wn*16 + g*4]);
  const int tsk4[4] = {tq.x, tq.y, tq.z, tq.w};

  // ring prologue: T0..T3 of expert 0
  issue16(strm,         0);
  issue16(strm +  8192, 1);
  issue16(strm + 16384, 2);
  issue16(strm + 24576, 3);

  f32x4 oacc[4];
  float m_[4], d_[4];
  #pragma unroll
  for (int j = 0; j < 4; j++){
    m_[j] = -1e30f; d_[j] = 0.f;
    #pragma unroll
    for (int ct = 0; ct < 4; ct++) oacc[ct][j] = 0.f;
  }

  f16x8 bfA[8], bfB[8];
  u32x4 pr[6];

#define LDBF(DST, SLOT) do { _Pragma("unroll") \
    for (int fnl = 0; fnl < 8; fnl++) \
      DST[fnl] = *reinterpret_cast<const f16x8*>(&ring[(SLOT)*12800 + (wn*8+fnl)*512 + lane*8]); \
  } while(0)
#define LDPR(FNP) do { _Pragma("unroll") \
    for (int i = 0; i < 6; i++) \
      pr[i] = *reinterpret_cast<const u32x4*>(&ring[(3+wn)*12800 + ((FNP)*6+i)*512 + lane*8]); \
  } while(0)
#define MFMA16(BUF, KC) do { _Pragma("unroll") \
    for (int fnl = 0; fnl < 8; fnl++){ \
      acc1[fnl][0] = __builtin_amdgcn_mfma_f32_16x16x32_f16(BUF[fnl], af[0][KC], acc1[fnl][0], 0,0,0); \
      acc1[fnl][1] = __builtin_amdgcn_mfma_f32_16x16x32_f16(BUF[fnl], af[1][KC], acc1[fnl][1], 0,0,0); \
    } } while(0)

  VMW(6); BARRIER;       // af + T0 staged (T1..T3 in flight)
  LDBF(bfA, 0);

  for (int e = 0; e < NEXP; e++){
    const unsigned short* es  = strm + (size_t)e*91136;
    const unsigned short* esn = (e == NEXP-1) ? strm : es + 91136;  // wrap keeps counts static
    f32x4 acc1[8][2] = {};

    VMW(4); BARRIER; issue16(es + 4*8192, 4);                LDBF(bfB, 1); MFMA16(bfA, 0);
    VMW(4); BARRIER; issue16(es + 5*8192, 0);                LDBF(bfA, 2); MFMA16(bfB, 1);
    VMW(4); BARRIER; issue16(es + 6*8192, 1);                LDBF(bfB, 3); MFMA16(bfA, 2);
    VMW(4); BARRIER; issue16(es + 7*8192, 2);                LDBF(bfA, 4); MFMA16(bfB, 3);
    VMW(4); BARRIER; issue24(es + 65536,  3);                LDBF(bfB, 0); MFMA16(bfA, 4);
    VMW(5); BARRIER; issueAux(es); issue24(es + 77824, 4);   LDBF(bfA, 1); MFMA16(bfB, 5);
    VMW(8); BARRIER; issue16(esn,         0);                LDBF(bfB, 2); MFMA16(bfA, 6);
    VMW(2); BARRIER; issue16(esn +  8192, 1);                LDPR(0);      MFMA16(bfB, 7);

    // ---- M phase: GEMM2 (pv + scores) from acc1 regs; WVp0/WVp1/aux staged ----
    VMW(4); BARRIER;
    issue16(esn + 16384, 2);
    f32x4 acc2[2][5] = {};
#define MSTEP(FNP, DOLOAD) do { \
    if (DOLOAD) LDPR(FNP); \
    f32x4 b1a = *reinterpret_cast<const f32x4*>(&ring[3*12800+12288 + wn*256 + (2*(FNP)+0)*32 + g*8]); \
    f32x4 b1b = *reinterpret_cast<const f32x4*>(&ring[3*12800+12288 + wn*256 + (2*(FNP)+1)*32 + g*8]); \
    _Pragma("unroll") \
    for (int half = 0; half < 2; half++){ \
      const int fnl = (FNP)*2 + half; \
      const f32x4 bb = half ? b1b : b1a; \
      f16x4 a0, a1; \
      _Pragma("unroll") \
      for (int j = 0; j < 4; j++){ \
        a0[j] = (_Float16)fmaxf(acc1[fnl][0][j] + bb[j], 0.f); \
        a1[j] = (_Float16)fmaxf(acc1[fnl][1][j] + bb[j], 0.f); \
      } \
      _Pragma("unroll") \
      for (int ct = 0; ct < 6; ct++){ \
        union { u32x4 v; struct { f16x4 lo, hi; } h; } u; u.v = pr[ct]; \
        const f16x4 bfr = half ? u.h.hi : u.h.lo; \
        const int ci = (ct < 5) ? ct : 4; \
        acc2[0][ci] = __builtin_amdgcn_mfma_f32_16x16x16f16(a0, bfr, acc2[0][ci], 0,0,0); \
        acc2[1][ci] = __builtin_amdgcn_mfma_f32_16x16x16f16(a1, bfr, acc2[1][ci], 0,0,0); \
      } \
    } } while(0)
    MSTEP(0, 0);
    MSTEP(1, 1);
    MSTEP(2, 1);
    MSTEP(3, 1);
#undef MSTEP

    // ---- X phase: exchange split-K partials; BOTH wn halves finalize 16 rows ----
    {
      unsigned char* ebW = &exch[(wm*2 + (wn^1))*3072];
      const int fmW = wn ^ 1;
      #pragma unroll
      for (int ct = 0; ct < 4; ct++){
        union { unsigned short s[4]; u32x2 v; } p;
        #pragma unroll
        for (int j = 0; j < 4; j++) p.s[j] = f2h(acc2[fmW][ct][j]);
        *reinterpret_cast<u32x2*>(ebW + ct*512 + lane*8) = p.v;
      }
      *reinterpret_cast<f32x4*>(ebW + 2048 + lane*16) = acc2[fmW][4];
    }
    LGKM0; VMW(4); BARRIER;
    issue16(esn + 24576, 3);
    LDBF(bfA, 0);                       // T0' for next expert's K0
    {
      const unsigned char* ebR = &exch[(wm*2 + wn)*3072];
      const float* b2f = reinterpret_cast<const float*>(&ring[4*12800 + 12288]);
      float b2c[4];
      #pragma unroll
      for (int ct = 0; ct < 4; ct++) b2c[ct] = b2f[ct*16 + c];
      const float b2s = b2f[64 + c];
      f32x4 pvv[4];
      #pragma unroll
      for (int ct = 0; ct < 4; ct++){
        union { u32x2 v; unsigned short s[4]; } p;
        p.v = *reinterpret_cast<const u32x2*>(ebR + ct*512 + lane*8);
        #pragma unroll
        for (int j = 0; j < 4; j++)
          pvv[ct][j] = acc2[wn][ct][j] + (float)__builtin_bit_cast(_Float16, p.s[j]) + b2c[ct];
      }
      const f32x4 scp = *reinterpret_cast<const f32x4*>(ebR + 2048 + lane*16);
      #pragma unroll
      for (int j = 0; j < 4; j++){
        const float sv = acc2[wn][4][j] + scp[j] + b2s;
        const float s  = __shfl(sv, (lane & 48) | tsk4[j]);
        const float mn = fmaxf(m_[j], s);
        const float al = __expf(m_[j] - mn);
        const float p  = __expf(s - mn);
        d_[j] = d_[j]*al + p;
        m_[j] = mn;
        #pragma unroll
        for (int ct = 0; ct < 4; ct++)
          oacc[ct][j] = oacc[ct][j]*al + p*pvv[ct][j];
      }
    }
  }
#undef MFMA16
#undef LDPR
#undef LDBF

  // ---- output: rows wm*32 + wn*16 + g*4 + j ----
  #pragma unroll
  for (int j = 0; j < 4; j++){
    const float inv = 1.f / d_[j];
    float* orow = out + (size_t)(row0 + wm*32 + wn*16 + g*4 + j)*64;
    #pragma unroll
    for (int ct = 0; ct < 4; ct++)
      orow[ct*16 + c] = oacc[ct][j]*inv;
  }
}

// ---------------------------------------------------------------------------
extern "C" void kernel_launch(void* const* d_in, const int* in_sizes, int n_in,
                              void* d_out, int out_size, void* d_ws, size_t ws_size,
                              hipStream_t hs)
{
  (void)in_sizes; (void)n_in; (void)out_size; (void)ws_size;
  const float* X   = (const float*)d_in[0];
  const int*   tsk = (const int*)  d_in[1];
  const float* W1  = (const float*)d_in[2];
  const float* b1  = (const float*)d_in[3];
  const float* W2  = (const float*)d_in[4];
  const float* b2  = (const float*)d_in[5];
  const float* Q   = (const float*)d_in[6];
  const float* Km  = (const float*)d_in[7];
  const float* Vm  = (const float*)d_in[8];
  float* out = (float*)d_out;

  unsigned short* strm = (unsigned short*)d_ws;

  prep_w1frag<<<dim3(256), dim3(256), 0, hs>>>(W1, strm);
  prep_wvp  <<<dim3(256), dim3(256), 0, hs>>>(W2, Vm, Km, Q, b1, b2, strm, out);
  moe_main  <<<dim3(NBLK), dim3(NTHR), 0, hs>>>(X, tsk, strm, out);
}

// Round 7
// 454.767 us; speedup vs baseline: 1.4491x; 1.4491x over previous
//
#include <hip/hip_runtime.h>
#include <hip/hip_fp16.h>

// B=32768, D_IN=256, H1=256, D_OUT=64, E=32, T=16
#define NTHR 512
#define BM   128
#define NBLK 256
#define NEXP 32

using f16x8 = __attribute__((ext_vector_type(8))) _Float16;
using f16x4 = __attribute__((ext_vector_type(4))) _Float16;
using f32x4 = __attribute__((ext_vector_type(4))) float;
using u32x4 = __attribute__((ext_vector_type(4))) unsigned int;
using u32x2 = __attribute__((ext_vector_type(2))) unsigned int;

// ---- per-expert stream (bytes): stride 182272 ----
//   [0)      8 x 16KB W1 fragment tiles (kc 0..7) = 4 x 32KB pairs
//   [131072) 24KB WVplus wn0 frags
//   [155648) 24KB WVplus wn1 frags   (wn0+wn1 = one contiguous 48KB M-stage)
//   [180224) 1KB b1 (256 f32)
//   [181248) 1KB b2v (80 f32 used)
static constexpr size_t ESTRIDE_B = 182272;   // = 91136 halves

__device__ __forceinline__ unsigned short f2h(float x){
  _Float16 h = (_Float16)x; return __builtin_bit_cast(unsigned short, h);
}

typedef __attribute__((address_space(3))) void lds_void;
typedef const __attribute__((address_space(1))) void glb_void;
__device__ __forceinline__ void gll16(const void* g, void* l){
  __builtin_amdgcn_global_load_lds((glb_void*)g, (lds_void*)l, 16, 0, 0);
}

#define VMW(N)  asm volatile("s_waitcnt vmcnt(" #N ")" ::: "memory")
#define LGKM0   asm volatile("s_waitcnt lgkmcnt(0)" ::: "memory")
#define SB      __builtin_amdgcn_sched_barrier(0)
#define BARRIER do { SB; __builtin_amdgcn_s_barrier(); SB; } while(0)

// ---------------------------------------------------------------------------
// prep 1: W1 [E][256][256] f32 -> per-(e,kc) 16KB fragment tile.
// frag(ct,l,j) = W1[e][kc*32 + (l>>4)*8 + j][ct*16 + (l&15)]
// ---------------------------------------------------------------------------
__global__ __launch_bounds__(256) void prep_w1frag(const float* __restrict__ W1,
                                                   unsigned short* __restrict__ strm){
  const int e = blockIdx.x >> 3, kc = blockIdx.x & 7;
  const float* se = W1 + (size_t)e*65536 + (size_t)kc*32*256;
  unsigned short* de = strm + (size_t)e*91136 + kc*8192;
  for (int fl = threadIdx.x; fl < 1024; fl += 256){
    const int ct = fl >> 6, l = fl & 63;
    const float* s0 = se + (size_t)((l>>4)*8)*256 + ct*16 + (l&15);
    union { unsigned short s[8]; u32x4 v; } h8;
    #pragma unroll
    for (int j = 0; j < 8; j++) h8.s[j] = f2h(s0[(size_t)j*256]);
    *reinterpret_cast<u32x4*>(&de[fl*8]) = h8.v;
  }
}

// ---------------------------------------------------------------------------
// prep 2: WVplus = [ W2@V (64 cols) | fp16-hi of W2@kt (16) | fp16-residual (16) ]
// fragment-pair layout for 16x16x16 B-op. Also b1, b2v into stream.
// grid: 256 blocks = (e, oct of 32 k2-rows)
// ---------------------------------------------------------------------------
__global__ __launch_bounds__(256) void prep_wvp(
    const float* __restrict__ W2, const float* __restrict__ V,
    const float* __restrict__ Km, const float* __restrict__ Q,
    const float* __restrict__ b1, const float* __restrict__ b2,
    unsigned short* __restrict__ strm, float* __restrict__ out)
{
  const int e = blockIdx.x >> 3, oct = blockIdx.x & 7;
  const int t = threadIdx.x;
  __shared__ float lv[64*64];     // V[e]
  __shared__ float ktlT[64*16];   // kt transposed: [i][t]
  __shared__ float lw2[32*64];    // W2 rows oct*32..+31

  for (int i = t; i < 1024; i += 256)
    *reinterpret_cast<float4*>(&lv[i*4]) = *reinterpret_cast<const float4*>(V + (size_t)e*4096 + i*4);
  for (int i = t; i < 512; i += 256)
    *reinterpret_cast<float4*>(&lw2[i*4]) = *reinterpret_cast<const float4*>(W2 + (size_t)e*16384 + (size_t)oct*2048 + i*4);
  #pragma unroll
  for (int pass = 0; pass < 4; pass++){
    const int id = t + pass*256;
    const int tt = id >> 6, i = id & 63;
    const float4* Kr = reinterpret_cast<const float4*>(Km + (size_t)(e*64 + i)*64);
    const float4* qr = reinterpret_cast<const float4*>(Q + tt*64);
    float s = 0.f;
    #pragma unroll
    for (int j = 0; j < 16; j++){ float4 a = Kr[j], b = qr[j]; s += a.x*b.x+a.y*b.y+a.z*b.z+a.w*b.w; }
    ktlT[i*16 + tt] = s;
  }
  __syncthreads();

  const int k2 = oct*32 + (t >> 3);
  const int cb = t & 7;
  const int c0 = cb*12;
  const float* w2r = &lw2[(t>>3)*64];
  const float* gp[3]; int gs[3]; bool gv[3];
  #pragma unroll
  for (int q = 0; q < 3; q++){
    const int cg = c0 + q*4;
    gv[q] = (cg < 80);
    if (cg < 64){ gp[q] = &lv[cg];        gs[q] = 64; }
    else        { gp[q] = &ktlT[cg - 64]; gs[q] = 16; }
  }
  float pv[12];
  #pragma unroll
  for (int n = 0; n < 12; n++) pv[n] = 0.f;
  for (int i = 0; i < 64; i++){
    const float w = w2r[i];
    #pragma unroll
    for (int q = 0; q < 3; q++){
      if (gv[q]){
        const float4 vq = *reinterpret_cast<const float4*>(gp[q] + i*gs[q]);
        pv[q*4+0] += w*vq.x; pv[q*4+1] += w*vq.y; pv[q*4+2] += w*vq.z; pv[q*4+3] += w*vq.w;
      }
    }
  }
  const int wn_ = k2 >> 7, fn = (k2 >> 4) & 7, fnp = fn >> 1, half = fn & 1;
  const int g2 = (k2 >> 2) & 3, jj = k2 & 3;
  unsigned short* fb = strm + (size_t)e*91136 + (wn_ ? 77824 : 65536);
  #pragma unroll
  for (int n = 0; n < 12; n++){
    const int cc = c0 + n;
    if (cc < 64){
      const int ct = cc >> 4, lc = cc & 15, l = g2*16 + lc;
      fb[(fnp*6+ct)*512 + l*8 + half*4 + jj] = f2h(pv[n]);
    } else if (cc < 80){
      const int lc = cc - 64, l = g2*16 + lc;
      const float s = pv[n];
      const unsigned short hi = f2h(s);
      const float rem = s - (float)__builtin_bit_cast(_Float16, hi);
      fb[(fnp*6+4)*512 + l*8 + half*4 + jj] = hi;
      fb[(fnp*6+5)*512 + l*8 + half*4 + jj] = f2h(rem);
    }
  }
  if (oct == 0){
    float* b1d = reinterpret_cast<float*>((char*)strm + (size_t)e*ESTRIDE_B + 180224);
    b1d[t] = b1[e*256 + t];
  }
  if (oct == 1 && t < 80){
    float s = 0.f;
    if (t < 64){ for (int i = 0; i < 64; i++) s += b2[e*64+i]*lv[i*64+t]; }
    else       { for (int i = 0; i < 64; i++) s += b2[e*64+i]*ktlT[i*16 + (t-64)]; }
    float* bd = reinterpret_cast<float*>((char*)strm + (size_t)e*ESTRIDE_B + 181248);
    bd[t] = s;
  }
  if (blockIdx.x == 0 && t == 0) out[2097152] = -10.24032768f;
}

// ---------------------------------------------------------------------------
// main kernel: 256 blocks x 512 thr, 1 block/CU (LDS-limited).
// LDS (148 KB): 3 x 32KB W1 slots | 48KB M-buffer (exch aliases its first
// 24KB) | 2 x 2KB aux (b1+b2v, per-expert ping-pong).
// 4 double-size GEMM1 phases + M + X = 7 barriers/expert; counted vmcnt
// (FIFO-derived: 6,4,4,6,6); all big buffers in LDS, NO persistent reg
// buffers beyond af[64] (R5/R6 lesson: allocator caps arch VGPRs at 128).
// ---------------------------------------------------------------------------
__global__ __launch_bounds__(NTHR, 2) __attribute__((amdgpu_waves_per_eu(2, 2)))
void moe_main(const float* __restrict__ X, const int* __restrict__ task,
              const unsigned short* __restrict__ strm, float* __restrict__ out)
{
  __shared__ unsigned short smem[75776];   // 151,552 B
  unsigned char* exch = (unsigned char*)smem + 98304;   // aliases Mbuf[0:24K)

  const int tid  = threadIdx.x;
  const int lane = tid & 63;
  const int wid  = tid >> 6;
  const int g    = lane >> 4;
  const int c    = lane & 15;
  const int wm   = wid >> 1, wn = wid & 1;   // 4x2 grid: 32 rows x 128 cols
  const int row0 = blockIdx.x * BM;

  auto issueG = [&](const unsigned short* src, int slot){   // 32KB, 4 vm-ops
    unsigned short* d = &smem[slot*16384];
    #pragma unroll
    for (int q = 0; q < 4; q++)
      gll16(src + q*4096 + tid*8, d + q*4096 + tid*8);
  };
  auto issueM = [&](const unsigned short* es_){             // 48KB, 6 vm-ops
    #pragma unroll
    for (int q = 0; q < 6; q++)
      gll16(es_ + 65536 + q*4096 + tid*8, &smem[49152 + q*4096 + tid*8]);
  };
  auto issueAux = [&](const unsigned short* es_, int k){    // 2KB, 2 vm-ops (wave-dup)
    gll16(es_ + 90112 + lane*8, &smem[73728 + k*1024 + lane*8]);
    gll16(es_ + 90624 + lane*8, &smem[73728 + k*1024 + 512 + lane*8]);
  };

  // ---- persistent X A-frags + tasks (completed & FIFO-drained before ring) ----
  f16x8 af[2][8];
  #pragma unroll
  for (int fm = 0; fm < 2; fm++){
    const float* xr = X + (size_t)(row0 + wm*32 + fm*16 + c)*256;
    #pragma unroll
    for (int kc = 0; kc < 8; kc++){
      const f32x4 v0 = *reinterpret_cast<const f32x4*>(xr + kc*32 + g*8);
      const f32x4 v1 = *reinterpret_cast<const f32x4*>(xr + kc*32 + g*8 + 4);
      union { unsigned short s[8]; f16x8 h; } h8;
      #pragma unroll
      for (int j = 0; j < 4; j++){ h8.s[j] = f2h(v0[j]); h8.s[4+j] = f2h(v1[j]); }
      af[fm][kc] = h8.h;
    }
  }
  const int4 tq = *reinterpret_cast<const int4*>(&task[row0 + wm*32 + wn*16 + g*4]);
  const int tsk4[4] = {tq.x, tq.y, tq.z, tq.w};

  VMW(0);   // drain af/task loads: ring FIFO below contains ONLY ring ops

  // ring prologue (order must match steady state: G0, aux, G1)
  issueG(strm, 0);
  issueAux(strm, 0);
  issueG(strm + 16384, 1);

  f32x4 oacc[4];
  float m_[4], d_[4];
  #pragma unroll
  for (int j = 0; j < 4; j++){
    m_[j] = -1e30f; d_[j] = 0.f;
    #pragma unroll
    for (int ct = 0; ct < 4; ct++) oacc[ct][j] = 0.f;
  }

#define G1PAIR(SLOT, P) do { \
    __builtin_amdgcn_s_setprio(1); \
    _Pragma("unroll") \
    for (int fnl = 0; fnl < 8; fnl++){ \
      const f16x8 bf = *reinterpret_cast<const f16x8*>(&smem[(SLOT)*16384 + (wn*8+fnl)*512 + lane*8]); \
      acc1[fnl][0] = __builtin_amdgcn_mfma_f32_16x16x32_f16(bf, af[0][2*(P)], acc1[fnl][0], 0,0,0); \
      acc1[fnl][1] = __builtin_amdgcn_mfma_f32_16x16x32_f16(bf, af[1][2*(P)], acc1[fnl][1], 0,0,0); \
    } \
    _Pragma("unroll") \
    for (int fnl = 0; fnl < 8; fnl++){ \
      const f16x8 bf = *reinterpret_cast<const f16x8*>(&smem[(SLOT)*16384 + 8192 + (wn*8+fnl)*512 + lane*8]); \
      acc1[fnl][0] = __builtin_amdgcn_mfma_f32_16x16x32_f16(bf, af[0][2*(P)+1], acc1[fnl][0], 0,0,0); \
      acc1[fnl][1] = __builtin_amdgcn_mfma_f32_16x16x32_f16(bf, af[1][2*(P)+1], acc1[fnl][1], 0,0,0); \
    } \
    __builtin_amdgcn_s_setprio(0); \
  } while(0)

#define MSTEP(FNP) do { \
    u32x4 pr[6]; \
    _Pragma("unroll") \
    for (int i = 0; i < 6; i++) \
      pr[i] = *reinterpret_cast<const u32x4*>(&smem[49152 + wn*12288 + ((FNP)*6+i)*512 + lane*8]); \
    const f32x4 b1a = *reinterpret_cast<const f32x4*>(b1f + wn*128 + (2*(FNP)+0)*16 + g*4); \
    const f32x4 b1b = *reinterpret_cast<const f32x4*>(b1f + wn*128 + (2*(FNP)+1)*16 + g*4); \
    __builtin_amdgcn_s_setprio(1); \
    _Pragma("unroll") \
    for (int half = 0; half < 2; half++){ \
      const int fnl = (FNP)*2 + half; \
      const f32x4 bb = half ? b1b : b1a; \
      f16x4 a0, a1; \
      _Pragma("unroll") \
      for (int j = 0; j < 4; j++){ \
        a0[j] = (_Float16)fmaxf(acc1[fnl][0][j] + bb[j], 0.f); \
        a1[j] = (_Float16)fmaxf(acc1[fnl][1][j] + bb[j], 0.f); \
      } \
      _Pragma("unroll") \
      for (int ct = 0; ct < 6; ct++){ \
        union { u32x4 v; struct { f16x4 lo, hi; } h; } u; u.v = pr[ct]; \
        const f16x4 bfr = half ? u.h.hi : u.h.lo; \
        const int ci = (ct < 5) ? ct : 4; \
        acc2[0][ci] = __builtin_amdgcn_mfma_f32_16x16x16f16(a0, bfr, acc2[0][ci], 0,0,0); \
        acc2[1][ci] = __builtin_amdgcn_mfma_f32_16x16x16f16(a1, bfr, acc2[1][ci], 0,0,0); \
      } \
    } \
    __builtin_amdgcn_s_setprio(0); \
  } while(0)

  int st = 0;
  for (int e = 0; e < NEXP; e++){
    const unsigned short* es  = strm + (size_t)e*91136;
    const unsigned short* esn = (e == NEXP-1) ? strm : es + 91136;  // wrap keeps counts static
    const int sA = st;
    const int sB = (sA + 1 < 3) ? sA + 1 : 0;
    const int sC = (sB + 1 < 3) ? sB + 1 : 0;
    const float* b1f = reinterpret_cast<const float*>(&smem[73728 + (e & 1)*1024]);
    f32x4 acc1[8][2] = {};

    // ---- GEMM1: 4 double phases (2 kc-tiles each) ----
    VMW(6); BARRIER; issueG(es + 2*16384, sC);                  G1PAIR(sA, 0);
    VMW(4); BARRIER; issueG(es + 3*16384, sA);                  G1PAIR(sB, 1);
    VMW(4); BARRIER; issueM(es);                                G1PAIR(sC, 2);
    VMW(6); BARRIER; issueG(esn, sB); issueAux(esn, (e+1)&1);   G1PAIR(sA, 3);

    // ---- M phase: GEMM2 (pv + scores) from acc1 regs, B-frags from Mbuf ----
    VMW(6); BARRIER;
    issueG(esn + 16384, sC);
    f32x4 acc2[2][5] = {};
    MSTEP(0); MSTEP(1); MSTEP(2); MSTEP(3);

    // ---- X phase: exchange split-K partials (exch aliases Mbuf -> barrier) ----
    BARRIER;
    {
      unsigned char* ebW = exch + (wm*2 + (wn^1))*3072;
      const int fmW = wn ^ 1;
      #pragma unroll
      for (int ct = 0; ct < 4; ct++){
        union { unsigned short s[4]; u32x2 v; } p;
        #pragma unroll
        for (int j = 0; j < 4; j++) p.s[j] = f2h(acc2[fmW][ct][j]);
        *reinterpret_cast<u32x2*>(ebW + ct*512 + lane*8) = p.v;
      }
      *reinterpret_cast<f32x4*>(ebW + 2048 + lane*16) = acc2[fmW][4];
    }
    LGKM0; BARRIER;
    {
      const unsigned char* ebR = exch + (wm*2 + wn)*3072;
      const float* b2f = b1f + 256;          // b2v block of this expert's aux
      float b2c[4];
      #pragma unroll
      for (int ct = 0; ct < 4; ct++) b2c[ct] = b2f[ct*16 + c];
      const float b2s = b2f[64 + c];
      f32x4 pvv[4];
      #pragma unroll
      for (int ct = 0; ct < 4; ct++){
        union { u32x2 v; unsigned short s[4]; } p;
        p.v = *reinterpret_cast<const u32x2*>(ebR + ct*512 + lane*8);
        #pragma unroll
        for (int j = 0; j < 4; j++)
          pvv[ct][j] = acc2[wn][ct][j] + (float)__builtin_bit_cast(_Float16, p.s[j]) + b2c[ct];
      }
      const f32x4 scp = *reinterpret_cast<const f32x4*>(ebR + 2048 + lane*16);
      #pragma unroll
      for (int j = 0; j < 4; j++){
        const float sv = acc2[wn][4][j] + scp[j] + b2s;
        const float s  = __shfl(sv, (lane & 48) | tsk4[j]);
        const float mn = fmaxf(m_[j], s);
        const float al = __expf(m_[j] - mn);
        const float p  = __expf(s - mn);
        d_[j] = d_[j]*al + p;
        m_[j] = mn;
        #pragma unroll
        for (int ct = 0; ct < 4; ct++)
          oacc[ct][j] = oacc[ct][j]*al + p*pvv[ct][j];
      }
    }
    st = sB;
  }
#undef MSTEP
#undef G1PAIR

  // ---- output: rows wm*32 + wn*16 + g*4 + j ----
  #pragma unroll
  for (int j = 0; j < 4; j++){
    const float inv = 1.f / d_[j];
    float* orow = out + (size_t)(row0 + wm*32 + wn*16 + g*4 + j)*64;
    #pragma unroll
    for (int ct = 0; ct < 4; ct++)
      orow[ct*16 + c] = oacc[ct][j]*inv;
  }
}

// ---------------------------------------------------------------------------
extern "C" void kernel_launch(void* const* d_in, const int* in_sizes, int n_in,
                              void* d_out, int out_size, void* d_ws, size_t ws_size,
                              hipStream_t hs)
{
  (void)in_sizes; (void)n_in; (void)out_size; (void)ws_size;
  const float* X   = (const float*)d_in[0];
  const int*   tsk = (const int*)  d_in[1];
  const float* W1  = (const float*)d_in[2];
  const float* b1  = (const float*)d_in[3];
  const float* W2  = (const float*)d_in[4];
  const float* b2  = (const float*)d_in[5];
  const float* Q   = (const float*)d_in[6];
  const float* Km  = (const float*)d_in[7];
  const float* Vm  = (const float*)d_in[8];
  float* out = (float*)d_out;

  unsigned short* strm = (unsigned short*)d_ws;

  prep_w1frag<<<dim3(256), dim3(256), 0, hs>>>(W1, strm);
  prep_wvp  <<<dim3(256), dim3(256), 0, hs>>>(W2, Vm, Km, Q, b1, b2, strm, out);
  moe_main  <<<dim3(NBLK), dim3(NTHR), 0, hs>>>(X, tsk, strm, out);
}

// Round 8
// 236.768 us; speedup vs baseline: 2.7833x; 1.9207x over previous
//
#include <hip/hip_runtime.h>
#include <hip/hip_fp16.h>

// B=32768, D_IN=256, H1=256, D_OUT=64, E=32, T=16
#define NTHR 512
#define BM   128
#define NBLK 256
#define NEXP 32

using f16x8 = __attribute__((ext_vector_type(8))) _Float16;
using f16x4 = __attribute__((ext_vector_type(4))) _Float16;
using f32x4 = __attribute__((ext_vector_type(4))) float;
using u32x4 = __attribute__((ext_vector_type(4))) unsigned int;
using u32x2 = __attribute__((ext_vector_type(2))) unsigned int;

// ---- per-expert stream (bytes): stride 182272 ----
//   [0)      8 x 16KB W1 fragment tiles (kc 0..7) = 4 x 32KB pairs
//   [131072) 24KB WVplus wn0 frags
//   [155648) 24KB WVplus wn1 frags   (wn0+wn1 = one contiguous 48KB M-stage)
//   [180224) 1KB b1 (256 f32)
//   [181248) 1KB b2v (80 f32 used)
static constexpr size_t ESTRIDE_B = 182272;   // = 91136 halves

__device__ __forceinline__ unsigned short f2h(float x){
  _Float16 h = (_Float16)x; return __builtin_bit_cast(unsigned short, h);
}

typedef __attribute__((address_space(3))) void lds_void;
typedef const __attribute__((address_space(1))) void glb_void;
__device__ __forceinline__ void gll16(const void* g, void* l){
  __builtin_amdgcn_global_load_lds((glb_void*)g, (lds_void*)l, 16, 0, 0);
}

#define VMW(N)  asm volatile("s_waitcnt vmcnt(" #N ")" ::: "memory")
#define LGKM0   asm volatile("s_waitcnt lgkmcnt(0)" ::: "memory")
#define SB      __builtin_amdgcn_sched_barrier(0)
#define BARRIER do { SB; __builtin_amdgcn_s_barrier(); SB; } while(0)

// ---------------------------------------------------------------------------
// prep 1: W1 [E][256][256] f32 -> per-(e,kc) 16KB fragment tile.
// frag(ct,l,j) = W1[e][kc*32 + (l>>4)*8 + j][ct*16 + (l&15)]
// ---------------------------------------------------------------------------
__global__ __launch_bounds__(256) void prep_w1frag(const float* __restrict__ W1,
                                                   unsigned short* __restrict__ strm){
  const int e = blockIdx.x >> 3, kc = blockIdx.x & 7;
  const float* se = W1 + (size_t)e*65536 + (size_t)kc*32*256;
  unsigned short* de = strm + (size_t)e*91136 + kc*8192;
  for (int fl = threadIdx.x; fl < 1024; fl += 256){
    const int ct = fl >> 6, l = fl & 63;
    const float* s0 = se + (size_t)((l>>4)*8)*256 + ct*16 + (l&15);
    union { unsigned short s[8]; u32x4 v; } h8;
    #pragma unroll
    for (int j = 0; j < 8; j++) h8.s[j] = f2h(s0[(size_t)j*256]);
    *reinterpret_cast<u32x4*>(&de[fl*8]) = h8.v;
  }
}

// ---------------------------------------------------------------------------
// prep 2: WVplus = [ W2@V (64 cols) | fp16-hi of W2@kt (16) | fp16-residual (16) ]
// fragment-pair layout for 16x16x16 B-op. Also b1, b2v into stream.
// grid: 256 blocks = (e, oct of 32 k2-rows)
// ---------------------------------------------------------------------------
__global__ __launch_bounds__(256) void prep_wvp(
    const float* __restrict__ W2, const float* __restrict__ V,
    const float* __restrict__ Km, const float* __restrict__ Q,
    const float* __restrict__ b1, const float* __restrict__ b2,
    unsigned short* __restrict__ strm, float* __restrict__ out)
{
  const int e = blockIdx.x >> 3, oct = blockIdx.x & 7;
  const int t = threadIdx.x;
  __shared__ float lv[64*64];     // V[e]
  __shared__ float ktlT[64*16];   // kt transposed: [i][t]
  __shared__ float lw2[32*64];    // W2 rows oct*32..+31

  for (int i = t; i < 1024; i += 256)
    *reinterpret_cast<float4*>(&lv[i*4]) = *reinterpret_cast<const float4*>(V + (size_t)e*4096 + i*4);
  for (int i = t; i < 512; i += 256)
    *reinterpret_cast<float4*>(&lw2[i*4]) = *reinterpret_cast<const float4*>(W2 + (size_t)e*16384 + (size_t)oct*2048 + i*4);
  #pragma unroll
  for (int pass = 0; pass < 4; pass++){
    const int id = t + pass*256;
    const int tt = id >> 6, i = id & 63;
    const float4* Kr = reinterpret_cast<const float4*>(Km + (size_t)(e*64 + i)*64);
    const float4* qr = reinterpret_cast<const float4*>(Q + tt*64);
    float s = 0.f;
    #pragma unroll
    for (int j = 0; j < 16; j++){ float4 a = Kr[j], b = qr[j]; s += a.x*b.x+a.y*b.y+a.z*b.z+a.w*b.w; }
    ktlT[i*16 + tt] = s;
  }
  __syncthreads();

  const int k2 = oct*32 + (t >> 3);
  const int cb = t & 7;
  const int c0 = cb*12;
  const float* w2r = &lw2[(t>>3)*64];
  const float* gp[3]; int gs[3]; bool gv[3];
  #pragma unroll
  for (int q = 0; q < 3; q++){
    const int cg = c0 + q*4;
    gv[q] = (cg < 80);
    if (cg < 64){ gp[q] = &lv[cg];        gs[q] = 64; }
    else        { gp[q] = &ktlT[cg - 64]; gs[q] = 16; }
  }
  float pv[12];
  #pragma unroll
  for (int n = 0; n < 12; n++) pv[n] = 0.f;
  for (int i = 0; i < 64; i++){
    const float w = w2r[i];
    #pragma unroll
    for (int q = 0; q < 3; q++){
      if (gv[q]){
        const float4 vq = *reinterpret_cast<const float4*>(gp[q] + i*gs[q]);
        pv[q*4+0] += w*vq.x; pv[q*4+1] += w*vq.y; pv[q*4+2] += w*vq.z; pv[q*4+3] += w*vq.w;
      }
    }
  }
  const int wn_ = k2 >> 7, fn = (k2 >> 4) & 7, fnp = fn >> 1, half = fn & 1;
  const int g2 = (k2 >> 2) & 3, jj = k2 & 3;
  unsigned short* fb = strm + (size_t)e*91136 + (wn_ ? 77824 : 65536);
  #pragma unroll
  for (int n = 0; n < 12; n++){
    const int cc = c0 + n;
    if (cc < 64){
      const int ct = cc >> 4, lc = cc & 15, l = g2*16 + lc;
      fb[(fnp*6+ct)*512 + l*8 + half*4 + jj] = f2h(pv[n]);
    } else if (cc < 80){
      const int lc = cc - 64, l = g2*16 + lc;
      const float s = pv[n];
      const unsigned short hi = f2h(s);
      const float rem = s - (float)__builtin_bit_cast(_Float16, hi);
      fb[(fnp*6+4)*512 + l*8 + half*4 + jj] = hi;
      fb[(fnp*6+5)*512 + l*8 + half*4 + jj] = f2h(rem);
    }
  }
  if (oct == 0){
    float* b1d = reinterpret_cast<float*>((char*)strm + (size_t)e*ESTRIDE_B + 180224);
    b1d[t] = b1[e*256 + t];
  }
  if (oct == 1 && t < 80){
    float s = 0.f;
    if (t < 64){ for (int i = 0; i < 64; i++) s += b2[e*64+i]*lv[i*64+t]; }
    else       { for (int i = 0; i < 64; i++) s += b2[e*64+i]*ktlT[i*16 + (t-64)]; }
    float* bd = reinterpret_cast<float*>((char*)strm + (size_t)e*ESTRIDE_B + 181248);
    bd[t] = s;
  }
  if (blockIdx.x == 0 && t == 0) out[2097152] = -10.24032768f;
}

// ---------------------------------------------------------------------------
// main kernel: 256 blocks x 512 thr, 1 block/CU (LDS-limited).
// LDS (148 KB): 3 x 32KB W1 slots | 48KB M-buffer (exch aliases its first
// 24KB) | 2 x 2KB aux. 7 barriers/expert, counted vmcnt.
// R8 fix: GEMM2 accumulators are named p0[5]/p1[5] and ALL accesses are
// compile-time static (wave-uniform if/else on wn) -- R7 spilled acc2[2][5]
// to scratch (714 MB of writes) due to runtime wn indexing (rule #20).
// ---------------------------------------------------------------------------
__global__ __launch_bounds__(NTHR, 2) __attribute__((amdgpu_waves_per_eu(2, 2)))
void moe_main(const float* __restrict__ X, const int* __restrict__ task,
              const unsigned short* __restrict__ strm, float* __restrict__ out)
{
  __shared__ unsigned short smem[75776];   // 151,552 B
  unsigned char* exch = (unsigned char*)smem + 98304;   // aliases Mbuf[0:24K)

  const int tid  = threadIdx.x;
  const int lane = tid & 63;
  const int wid  = tid >> 6;
  const int g    = lane >> 4;
  const int c    = lane & 15;
  const int wm   = wid >> 1, wn = wid & 1;   // 4x2 grid: 32 rows x 128 cols
  const int row0 = blockIdx.x * BM;

  auto issueG = [&](const unsigned short* src, int slot){   // 32KB, 4 vm-ops
    unsigned short* d = &smem[slot*16384];
    #pragma unroll
    for (int q = 0; q < 4; q++)
      gll16(src + q*4096 + tid*8, d + q*4096 + tid*8);
  };
  auto issueM = [&](const unsigned short* es_){             // 48KB, 6 vm-ops
    #pragma unroll
    for (int q = 0; q < 6; q++)
      gll16(es_ + 65536 + q*4096 + tid*8, &smem[49152 + q*4096 + tid*8]);
  };
  auto issueAux = [&](const unsigned short* es_, int k){    // 2KB, 2 vm-ops (wave-dup)
    gll16(es_ + 90112 + lane*8, &smem[73728 + k*1024 + lane*8]);
    gll16(es_ + 90624 + lane*8, &smem[73728 + k*1024 + 512 + lane*8]);
  };

  // ---- persistent X A-frags + tasks (completed & FIFO-drained before ring) ----
  f16x8 af[2][8];
  #pragma unroll
  for (int fm = 0; fm < 2; fm++){
    const float* xr = X + (size_t)(row0 + wm*32 + fm*16 + c)*256;
    #pragma unroll
    for (int kc = 0; kc < 8; kc++){
      const f32x4 v0 = *reinterpret_cast<const f32x4*>(xr + kc*32 + g*8);
      const f32x4 v1 = *reinterpret_cast<const f32x4*>(xr + kc*32 + g*8 + 4);
      union { unsigned short s[8]; f16x8 h; } h8;
      #pragma unroll
      for (int j = 0; j < 4; j++){ h8.s[j] = f2h(v0[j]); h8.s[4+j] = f2h(v1[j]); }
      af[fm][kc] = h8.h;
    }
  }
  const int4 tq = *reinterpret_cast<const int4*>(&task[row0 + wm*32 + wn*16 + g*4]);
  const int tsk4[4] = {tq.x, tq.y, tq.z, tq.w};

  VMW(0);   // drain af/task loads: ring FIFO below contains ONLY ring ops

  // ring prologue (order must match steady state: G0, aux, G1)
  issueG(strm, 0);
  issueAux(strm, 0);
  issueG(strm + 16384, 1);

  f32x4 oacc[4];
  float m_[4], d_[4];
  #pragma unroll
  for (int j = 0; j < 4; j++){
    m_[j] = -1e30f; d_[j] = 0.f;
    #pragma unroll
    for (int ct = 0; ct < 4; ct++) oacc[ct][j] = 0.f;
  }

#define G1PAIR(SLOT, P) do { \
    __builtin_amdgcn_s_setprio(1); \
    _Pragma("unroll") \
    for (int fnl = 0; fnl < 8; fnl++){ \
      const f16x8 bf = *reinterpret_cast<const f16x8*>(&smem[(SLOT)*16384 + (wn*8+fnl)*512 + lane*8]); \
      acc1[fnl][0] = __builtin_amdgcn_mfma_f32_16x16x32_f16(bf, af[0][2*(P)], acc1[fnl][0], 0,0,0); \
      acc1[fnl][1] = __builtin_amdgcn_mfma_f32_16x16x32_f16(bf, af[1][2*(P)], acc1[fnl][1], 0,0,0); \
    } \
    _Pragma("unroll") \
    for (int fnl = 0; fnl < 8; fnl++){ \
      const f16x8 bf = *reinterpret_cast<const f16x8*>(&smem[(SLOT)*16384 + 8192 + (wn*8+fnl)*512 + lane*8]); \
      acc1[fnl][0] = __builtin_amdgcn_mfma_f32_16x16x32_f16(bf, af[0][2*(P)+1], acc1[fnl][0], 0,0,0); \
      acc1[fnl][1] = __builtin_amdgcn_mfma_f32_16x16x32_f16(bf, af[1][2*(P)+1], acc1[fnl][1], 0,0,0); \
    } \
    __builtin_amdgcn_s_setprio(0); \
  } while(0)

// GEMM2 step: accumulate into named p0[5] (rows fm=0) / p1[5] (rows fm=1)
#define MSTEP(FNP) do { \
    u32x4 pr[6]; \
    _Pragma("unroll") \
    for (int i = 0; i < 6; i++) \
      pr[i] = *reinterpret_cast<const u32x4*>(&smem[49152 + wn*12288 + ((FNP)*6+i)*512 + lane*8]); \
    const f32x4 b1a = *reinterpret_cast<const f32x4*>(b1f + wn*128 + (2*(FNP)+0)*16 + g*4); \
    const f32x4 b1b = *reinterpret_cast<const f32x4*>(b1f + wn*128 + (2*(FNP)+1)*16 + g*4); \
    __builtin_amdgcn_s_setprio(1); \
    _Pragma("unroll") \
    for (int half = 0; half < 2; half++){ \
      const int fnl = (FNP)*2 + half; \
      const f32x4 bb = half ? b1b : b1a; \
      f16x4 a0, a1; \
      _Pragma("unroll") \
      for (int j = 0; j < 4; j++){ \
        a0[j] = (_Float16)fmaxf(acc1[fnl][0][j] + bb[j], 0.f); \
        a1[j] = (_Float16)fmaxf(acc1[fnl][1][j] + bb[j], 0.f); \
      } \
      _Pragma("unroll") \
      for (int ct = 0; ct < 6; ct++){ \
        union { u32x4 v; struct { f16x4 lo, hi; } h; } u; u.v = pr[ct]; \
        const f16x4 bfr = half ? u.h.hi : u.h.lo; \
        const int ci = (ct < 5) ? ct : 4; \
        p0[ci] = __builtin_amdgcn_mfma_f32_16x16x16f16(a0, bfr, p0[ci], 0,0,0); \
        p1[ci] = __builtin_amdgcn_mfma_f32_16x16x16f16(a1, bfr, p1[ci], 0,0,0); \
      } \
    } \
    __builtin_amdgcn_s_setprio(0); \
  } while(0)

// X-phase helpers: ALL register indices compile-time constant.
#define XWRITE(ACC, EB) do { \
    _Pragma("unroll") \
    for (int ct = 0; ct < 4; ct++){ \
      union { unsigned short s[4]; u32x2 v; } p_; \
      _Pragma("unroll") \
      for (int j = 0; j < 4; j++) p_.s[j] = f2h(ACC[ct][j]); \
      *reinterpret_cast<u32x2*>((EB) + ct*512 + lane*8) = p_.v; \
    } \
    *reinterpret_cast<f32x4*>((EB) + 2048 + lane*16) = ACC[4]; \
  } while(0)

#define XFINAL(ACC, EB) do { \
    float b2c[4]; \
    _Pragma("unroll") \
    for (int ct = 0; ct < 4; ct++) b2c[ct] = b2f[ct*16 + c]; \
    const float b2s = b2f[64 + c]; \
    f32x4 pvv[4]; \
    _Pragma("unroll") \
    for (int ct = 0; ct < 4; ct++){ \
      union { u32x2 v; unsigned short s[4]; } p_; \
      p_.v = *reinterpret_cast<const u32x2*>((EB) + ct*512 + lane*8); \
      _Pragma("unroll") \
      for (int j = 0; j < 4; j++) \
        pvv[ct][j] = ACC[ct][j] + (float)__builtin_bit_cast(_Float16, p_.s[j]) + b2c[ct]; \
    } \
    const f32x4 scp = *reinterpret_cast<const f32x4*>((EB) + 2048 + lane*16); \
    _Pragma("unroll") \
    for (int j = 0; j < 4; j++){ \
      const float sv = ACC[4][j] + scp[j] + b2s; \
      const float s  = __shfl(sv, (lane & 48) | tsk4[j]); \
      const float mn = fmaxf(m_[j], s); \
      const float al = __expf(m_[j] - mn); \
      const float p  = __expf(s - mn); \
      d_[j] = d_[j]*al + p; \
      m_[j] = mn; \
      _Pragma("unroll") \
      for (int ct = 0; ct < 4; ct++) \
        oacc[ct][j] = oacc[ct][j]*al + p*pvv[ct][j]; \
    } \
  } while(0)

  int st = 0;
  for (int e = 0; e < NEXP; e++){
    const unsigned short* es  = strm + (size_t)e*91136;
    const unsigned short* esn = (e == NEXP-1) ? strm : es + 91136;  // wrap keeps counts static
    const int sA = st;
    const int sB = (sA + 1 < 3) ? sA + 1 : 0;
    const int sC = (sB + 1 < 3) ? sB + 1 : 0;
    const float* b1f = reinterpret_cast<const float*>(&smem[73728 + (e & 1)*1024]);
    f32x4 acc1[8][2] = {};

    // ---- GEMM1: 4 double phases (2 kc-tiles each) ----
    VMW(6); BARRIER; issueG(es + 2*16384, sC);                  G1PAIR(sA, 0);
    VMW(4); BARRIER; issueG(es + 3*16384, sA);                  G1PAIR(sB, 1);
    VMW(4); BARRIER; issueM(es);                                G1PAIR(sC, 2);
    VMW(6); BARRIER; issueG(esn, sB); issueAux(esn, (e+1)&1);   G1PAIR(sA, 3);

    // ---- M phase: GEMM2 (pv + scores) from acc1 regs, B-frags from Mbuf ----
    VMW(6); BARRIER;
    issueG(esn + 16384, sC);
    f32x4 p0[5] = {}, p1[5] = {};
    MSTEP(0); MSTEP(1); MSTEP(2); MSTEP(3);

    // ---- X phase: exchange split-K partials (exch aliases Mbuf -> barrier) ----
    BARRIER;
    if (wn == 0){
      XWRITE(p1, exch + (wm*2 + 1)*3072);
    } else {
      XWRITE(p0, exch + (wm*2 + 0)*3072);
    }
    LGKM0; BARRIER;
    {
      const float* b2f = b1f + 256;          // b2v block of this expert's aux
      if (wn == 0){
        XFINAL(p0, exch + (wm*2 + 0)*3072);
      } else {
        XFINAL(p1, exch + (wm*2 + 1)*3072);
      }
    }
    st = sB;
  }
#undef XFINAL
#undef XWRITE
#undef MSTEP
#undef G1PAIR

  // ---- output: rows wm*32 + wn*16 + g*4 + j ----
  #pragma unroll
  for (int j = 0; j < 4; j++){
    const float inv = 1.f / d_[j];
    float* orow = out + (size_t)(row0 + wm*32 + wn*16 + g*4 + j)*64;
    #pragma unroll
    for (int ct = 0; ct < 4; ct++)
      orow[ct*16 + c] = oacc[ct][j]*inv;
  }
}

// ---------------------------------------------------------------------------
extern "C" void kernel_launch(void* const* d_in, const int* in_sizes, int n_in,
                              void* d_out, int out_size, void* d_ws, size_t ws_size,
                              hipStream_t hs)
{
  (void)in_sizes; (void)n_in; (void)out_size; (void)ws_size;
  const float* X   = (const float*)d_in[0];
  const int*   tsk = (const int*)  d_in[1];
  const float* W1  = (const float*)d_in[2];
  const float* b1  = (const float*)d_in[3];
  const float* W2  = (const float*)d_in[4];
  const float* b2  = (const float*)d_in[5];
  const float* Q   = (const float*)d_in[6];
  const float* Km  = (const float*)d_in[7];
  const float* Vm  = (const float*)d_in[8];
  float* out = (float*)d_out;

  unsigned short* strm = (unsigned short*)d_ws;

  prep_w1frag<<<dim3(256), dim3(256), 0, hs>>>(W1, strm);
  prep_wvp  <<<dim3(256), dim3(256), 0, hs>>>(W2, Vm, Km, Q, b1, b2, strm, out);
  moe_main  <<<dim3(NBLK), dim3(NTHR), 0, hs>>>(X, tsk, strm, out);
}